// Round 4
// baseline (350.373 us; speedup 1.0000x reference)
//
#include <hip/hip_runtime.h>
#include <hip/hip_bf16.h>

typedef __bf16 bf16x8 __attribute__((ext_vector_type(8)));
typedef __bf16 bf16x4 __attribute__((ext_vector_type(4)));
typedef float  f32x4  __attribute__((ext_vector_type(4)));

#define MFMA16(a, b, c) __builtin_amdgcn_mfma_f32_16x16x32_bf16((a), (b), (c), 0, 0, 0)

#define SEGS_PER_BLOCK 3

// ---------------------------------------------------------------------------
// K1: block 240: exclusive scan of sizes; blocks 0-47: conv weight pack;
// blocks 48-239: lin_w hi/lo pack.
// B-frag for 16x16x32: lane holds B[k = (lane>>4)*8 + j][n = lane&15], j=0..7.
// ---------------------------------------------------------------------------
__global__ void k_prep(const int* __restrict__ sizes, int* __restrict__ offsets,
                       const float* __restrict__ w0, const float* __restrict__ w1,
                       const float* __restrict__ w2, const float* __restrict__ lw,
                       __bf16* __restrict__ Wpack,
                       __bf16* __restrict__ Lhi, __bf16* __restrict__ Llo) {
  const int bid = blockIdx.x, t = threadIdx.x;
  if (bid == 240) {
    __shared__ int part[256];
    const int base = t * 32;
    int v[32];
    int s = 0;
#pragma unroll
    for (int i = 0; i < 32; ++i) { v[i] = sizes[base + i]; s += v[i]; }
    part[t] = s;
    __syncthreads();
    for (int d = 1; d < 256; d <<= 1) {
      int add = (t >= d) ? part[t - d] : 0;
      __syncthreads();
      part[t] += add;
      __syncthreads();
    }
    int run = (t == 0) ? 0 : part[t - 1];
#pragma unroll
    for (int i = 0; i < 32; ++i) { offsets[base + i] = run; run += v[i]; }
  } else if (bid < 48) {
    const int nt = bid, sl = nt >> 3, f = nt & 7;
    const int kt = t >> 6, lane = t & 63;
    const float* src; int kw, jj;
    if      (sl == 0) { src = w0; kw = 1; jj = 0; }
    else if (sl == 1) { src = w1; kw = 2; jj = 0; }
    else if (sl == 2) { src = w1; kw = 2; jj = 1; }
    else if (sl == 3) { src = w2; kw = 3; jj = 0; }
    else if (sl == 4) { src = w2; kw = 3; jj = 1; }
    else              { src = w2; kw = 3; jj = 2; }
    const int feat  = f * 16 + (lane & 15);
    const int cbase = kt * 32 + ((lane >> 4) << 3);
    __bf16* dst = Wpack + ((((nt * 4 + kt) << 6) + lane) << 3);
#pragma unroll
    for (int j = 0; j < 8; ++j)
      dst[j] = (__bf16)src[(feat * 128 + cbase + j) * kw + jj];
  } else {
    const int idx = (bid - 48) * 256 + t;          // 0..49151
    const int j = idx & 7, lane = (idx >> 3) & 63, rest = idx >> 9;  // 0..95
    const int kt = rest % 12, nt = rest / 12;
    const int o = nt * 16 + (lane & 15);
    const int q = kt * 32 + ((lane >> 4) << 3) + j;
    const float v = lw[o * 384 + q];
    const __bf16 hi = (__bf16)v;
    Lhi[idx] = hi;
    Llo[idx] = (__bf16)(v - (float)hi);
  }
}

// ---------------------------------------------------------------------------
// K2: fused conv (6 slices via MFMA) + shifted combine + relu + ragged max.
// G=3 segments per block: B-fragments hoisted to VGPRs outside the segment
// loop (L2 weight traffic /3, barriers /3).
// C/D layout (m89-verified): col = lane&15, row = (lane>>4)*4 + reg.
// ---------------------------------------------------------------------------
__global__ __launch_bounds__(256, 3)
void k_conv(const float* __restrict__ x, const int* __restrict__ sizes,
            const int* __restrict__ offsets,
            const float* __restrict__ cb0, const float* __restrict__ cb1,
            const float* __restrict__ cb2,
            const bf16x8* __restrict__ Wpack,
            __bf16* __restrict__ Phi, __bf16* __restrict__ Plo) {
  __shared__ __bf16 xh[SEGS_PER_BLOCK][64 * 136];   // 3 x 17.4 KB = 52.2 KB
  const int b0 = blockIdx.x * SEGS_PER_BLOCK;
  const int segs = min(SEGS_PER_BLOCK, 8192 - b0);
  const int t = threadIdx.x;

  int  sz[SEGS_PER_BLOCK];
  long ofs[SEGS_PER_BLOCK];
#pragma unroll
  for (int g = 0; g < SEGS_PER_BLOCK; ++g) {
    sz[g]  = (g < segs) ? sizes[b0 + g] : 0;
    ofs[g] = (g < segs) ? (long)offsets[b0 + g] : 0;
  }

  // ---- stage: f32 -> bf16 into LDS (float4 loads, b64 stores) ----
#pragma unroll
  for (int g = 0; g < SEGS_PER_BLOCK; ++g) {
    if (g >= segs) break;
    const int s = sz[g];
    const int MT = (s + 15) >> 4;
    const long off = ofs[g];
    __bf16* base = &xh[g][0];
    const int quads = s << 5;                       // s*128/4
    for (int qi = t; qi < quads; qi += 256) {
      const int r = qi >> 5, c = (qi & 31) << 2;
      const float4 v = *(const float4*)(x + (off + r) * 128 + c);
      bf16x4 h; h[0] = (__bf16)v.x; h[1] = (__bf16)v.y;
                h[2] = (__bf16)v.z; h[3] = (__bf16)v.w;
      *(bf16x4*)&base[r * 136 + c] = h;
    }
    const int padquads = ((MT << 4) - s) << 5;
    for (int qi = t; qi < padquads; qi += 256) {
      const int e = (qi << 2) + (s << 7), r = e >> 7, c = e & 127;
      *(bf16x4*)&base[r * 136 + c] =
          bf16x4{(__bf16)0.f, (__bf16)0.f, (__bf16)0.f, (__bf16)0.f};
    }
  }
  __syncthreads();

  const int wid = t >> 6, lane = t & 63;
  const int lo16 = lane & 15, g16 = lane >> 4;

#pragma unroll
  for (int fi = 0; fi < 2; ++fi) {
    const int ft = wid + (fi << 2);
    const int feat = ft * 16 + lo16;
#pragma unroll
    for (int pass = 0; pass < 2; ++pass) {
      // pass 0: slices w1j0, w2j0, w2j1 (pools 1,2)
      // pass 1: slices w3j0, w3j1, w3j2 (pool 3)
      bf16x8 bf[3][4];   // [sl][kt] held across segments: 48 VGPRs
#pragma unroll
      for (int sl = 0; sl < 3; ++sl)
#pragma unroll
        for (int kt = 0; kt < 4; ++kt)
          bf[sl][kt] = Wpack[((((pass * 3 + sl) * 8 + ft) * 4 + kt) << 6) + lane];

#pragma unroll
      for (int g = 0; g < SEGS_PER_BLOCK; ++g) {
        if (g >= segs) break;
        const int s = sz[g];
        const int MT = (s + 15) >> 4;
        const __bf16* base = &xh[g][0];

        f32x4 acc[4][3];
#pragma unroll
        for (int mt = 0; mt < 4; ++mt)
#pragma unroll
          for (int sl = 0; sl < 3; ++sl)
            acc[mt][sl] = f32x4{0.f, 0.f, 0.f, 0.f};

#pragma unroll
        for (int kt = 0; kt < 4; ++kt) {
#pragma unroll
          for (int mt = 0; mt < 4; ++mt) {
            if (mt < MT) {   // uniform per segment
              const bf16x8 a =
                  *(const bf16x8*)&base[(mt * 16 + lo16) * 136 + kt * 32 + (g16 << 3)];
              acc[mt][0] = MFMA16(a, bf[0][kt], acc[mt][0]);
              acc[mt][1] = MFMA16(a, bf[1][kt], acc[mt][1]);
              acc[mt][2] = MFMA16(a, bf[2][kt], acc[mt][2]);
            }
          }
        }

        if (pass == 0) {
          float m1 = -1e30f, m2 = -1e30f;
#pragma unroll
          for (int mt = 0; mt < 4; ++mt) {
            if (mt >= MT) continue;  // uniform
#pragma unroll
            for (int v = 0; v < 4; ++v) {
              float s2v;   // slice2 shifted +1 row
              if (v < 3) {
                s2v = acc[mt][2][v + 1];
              } else {
                const float up = __shfl(acc[mt][2][0], lane + 16);
                const float dn = __shfl(acc[(mt < 3) ? mt + 1 : mt][2][0], lo16);
                s2v = (g16 < 3) ? up : dn;
              }
              const int lrow = mt * 16 + g16 * 4 + v;
              if (lrow < s)     m1 = fmaxf(m1, acc[mt][0][v]);
              if (lrow < s - 1) m2 = fmaxf(m2, acc[mt][1][v] + s2v);
            }
          }
          m1 = fmaxf(m1, __shfl_xor(m1, 16)); m1 = fmaxf(m1, __shfl_xor(m1, 32));
          m2 = fmaxf(m2, __shfl_xor(m2, 16)); m2 = fmaxf(m2, __shfl_xor(m2, 32));
          if (g16 == 0) {
            // max(relu(h)) == relu(max(Y)+b): bias row-constant, relu monotone
            const float p1 = fmaxf(m1 + cb0[feat], 0.f);
            const float p2 = fmaxf(m2 + cb1[feat], 0.f);
            const __bf16 h1 = (__bf16)p1, h2 = (__bf16)p2;
            const long row = (long)(b0 + g) * 384;
            Phi[row + feat]       = h1;
            Plo[row + feat]       = (__bf16)(p1 - (float)h1);
            Phi[row + 128 + feat] = h2;
            Plo[row + 128 + feat] = (__bf16)(p2 - (float)h2);
          }
        } else {
          float m3 = -1e30f;
#pragma unroll
          for (int mt = 0; mt < 4; ++mt) {
            if (mt >= MT) continue;  // uniform
#pragma unroll
            for (int v = 0; v < 4; ++v) {
              float s4v;   // slice4 (local 1) shifted +1 row
              if (v < 3) {
                s4v = acc[mt][1][v + 1];
              } else {
                const float up = __shfl(acc[mt][1][0], lane + 16);
                const float dn = __shfl(acc[(mt < 3) ? mt + 1 : mt][1][0], lo16);
                s4v = (g16 < 3) ? up : dn;
              }
              float s5v;   // slice5 (local 2) shifted +2 rows
              if (v < 2) {
                s5v = acc[mt][2][v + 2];
              } else {
                const float up = __shfl(acc[mt][2][v - 2], lane + 16);
                const float dn = __shfl(acc[(mt < 3) ? mt + 1 : mt][2][v - 2], lo16);
                s5v = (g16 < 3) ? up : dn;
              }
              const int lrow = mt * 16 + g16 * 4 + v;
              if (lrow < s - 2) m3 = fmaxf(m3, acc[mt][0][v] + s4v + s5v);
            }
          }
          m3 = fmaxf(m3, __shfl_xor(m3, 16)); m3 = fmaxf(m3, __shfl_xor(m3, 32));
          if (g16 == 0) {
            const float p3 = fmaxf(m3 + cb2[feat], 0.f);
            const __bf16 h3 = (__bf16)p3;
            const long row = (long)(b0 + g) * 384;
            Phi[row + 256 + feat] = h3;
            Plo[row + 256 + feat] = (__bf16)(p3 - (float)h3);
          }
        }
      }
    }
  }
}

// ---------------------------------------------------------------------------
// K3: out = tanh(P[8192,384] @ lin_w^T + lin_b), split bf16 MFMA (3 products:
// Ph*Wh + Pl*Wh + Ph*Wl -> ~fp32 accuracy).  512 blocks x 16 batch rows.
// ---------------------------------------------------------------------------
__global__ __launch_bounds__(256, 4)
void k_lin(const __bf16* __restrict__ Phi, const __bf16* __restrict__ Plo,
           const bf16x8* __restrict__ Lhi, const bf16x8* __restrict__ Llo,
           const float* __restrict__ lb, float* __restrict__ out) {
  __shared__ __bf16 ph[16 * 392];   // [row][384 + 8 pad]
  __shared__ __bf16 pl[16 * 392];
  const int blk = blockIdx.x, t = threadIdx.x;
  const long rbase = (long)blk * 16;
#pragma unroll
  for (int i = 0; i < 3; ++i) {
    const int ci = t + (i << 8);
    const int r = ci / 48, cc = ci % 48;
    *(int4*)&ph[r * 392 + (cc << 3)] = *(const int4*)&Phi[(rbase + r) * 384 + (cc << 3)];
    *(int4*)&pl[r * 392 + (cc << 3)] = *(const int4*)&Plo[(rbase + r) * 384 + (cc << 3)];
  }
  __syncthreads();
  const int wid = t >> 6, lane = t & 63;
  const int lo16 = lane & 15, g = lane >> 4;
#pragma unroll
  for (int ni = 0; ni < 2; ++ni) {
    const int nt = wid + (ni << 2);
    f32x4 acc = f32x4{0.f, 0.f, 0.f, 0.f};
#pragma unroll
    for (int kt = 0; kt < 12; ++kt) {
      const bf16x8 bh = Lhi[((nt * 12 + kt) << 6) + lane];
      const bf16x8 bl = Llo[((nt * 12 + kt) << 6) + lane];
      const int aoff = lo16 * 392 + kt * 32 + (g << 3);
      const bf16x8 ah = *(const bf16x8*)&ph[aoff];
      const bf16x8 al = *(const bf16x8*)&pl[aoff];
      acc = MFMA16(ah, bh, acc);
      acc = MFMA16(al, bh, acc);
      acc = MFMA16(ah, bl, acc);
    }
    const int o = nt * 16 + lo16;
    const float bias = lb[o];
#pragma unroll
    for (int v = 0; v < 4; ++v) {
      const int r = g * 4 + v;
      const float val = acc[v] + bias;
      out[(rbase + r) * 128 + o] = 1.f - 2.f / (__expf(2.f * val) + 1.f);
    }
  }
}

// ---------------------------------------------------------------------------
extern "C" void kernel_launch(void* const* d_in, const int* in_sizes, int n_in,
                              void* d_out, int out_size, void* d_ws, size_t ws_size,
                              hipStream_t stream) {
  const float* x   = (const float*)d_in[0];
  const int* sizes = (const int*)d_in[1];
  const float* w0  = (const float*)d_in[2];
  const float* cb0 = (const float*)d_in[3];
  const float* w1  = (const float*)d_in[4];
  const float* cb1 = (const float*)d_in[5];
  const float* w2  = (const float*)d_in[6];
  const float* cb2 = (const float*)d_in[7];
  const float* lw  = (const float*)d_in[8];
  const float* lb  = (const float*)d_in[9];

  char* ws = (char*)d_ws;
  size_t o = 0;
  int*    offsets = (int*)ws;                 o += 32768;
  __bf16* Wpack   = (__bf16*)(ws + o);        o += 196608;     // 48*4*64*8*2
  __bf16* Lhi     = (__bf16*)(ws + o);        o += 98304;      // 8*12*64*8*2
  __bf16* Llo     = (__bf16*)(ws + o);        o += 98304;
  __bf16* Phi     = (__bf16*)(ws + o);        o += 8192L * 384 * 2;
  __bf16* Plo     = (__bf16*)(ws + o);        o += 8192L * 384 * 2;

  const int nconv = (8192 + SEGS_PER_BLOCK - 1) / SEGS_PER_BLOCK;  // 2731
  k_prep<<<241, 256, 0, stream>>>(sizes, offsets, w0, w1, w2, lw, Wpack, Lhi, Llo);
  k_conv<<<nconv, 256, 0, stream>>>(x, sizes, offsets, cb0, cb1, cb2,
                                    (const bf16x8*)Wpack, Phi, Plo);
  k_lin<<<512, 256, 0, stream>>>(Phi, Plo, (const bf16x8*)Lhi,
                                 (const bf16x8*)Llo, lb, (float*)d_out);
}

// Round 5
// 326.448 us; speedup vs baseline: 1.0733x; 1.0733x over previous
//
#include <hip/hip_runtime.h>
#include <hip/hip_bf16.h>

typedef __bf16 bf16x8 __attribute__((ext_vector_type(8)));
typedef __bf16 bf16x4 __attribute__((ext_vector_type(4)));
typedef float  f32x4  __attribute__((ext_vector_type(4)));

#define MFMA16(a, b, c) __builtin_amdgcn_mfma_f32_16x16x32_bf16((a), (b), (c), 0, 0, 0)

// ---------------------------------------------------------------------------
// K1: block 240: exclusive scan of sizes; blocks 0-47: conv weight pack;
// blocks 48-239: lin_w hi/lo pack.
// B-frag for 16x16x32: lane holds B[k = (lane>>4)*8 + j][n = lane&15], j=0..7.
// ---------------------------------------------------------------------------
__global__ void k_prep(const int* __restrict__ sizes, int* __restrict__ offsets,
                       const float* __restrict__ w0, const float* __restrict__ w1,
                       const float* __restrict__ w2, const float* __restrict__ lw,
                       __bf16* __restrict__ Wpack,
                       __bf16* __restrict__ Lhi, __bf16* __restrict__ Llo) {
  const int bid = blockIdx.x, t = threadIdx.x;
  if (bid == 240) {
    __shared__ int part[256];
    const int base = t * 32;
    int v[32];
    int s = 0;
#pragma unroll
    for (int i = 0; i < 32; ++i) { v[i] = sizes[base + i]; s += v[i]; }
    part[t] = s;
    __syncthreads();
    for (int d = 1; d < 256; d <<= 1) {
      int add = (t >= d) ? part[t - d] : 0;
      __syncthreads();
      part[t] += add;
      __syncthreads();
    }
    int run = (t == 0) ? 0 : part[t - 1];
#pragma unroll
    for (int i = 0; i < 32; ++i) { offsets[base + i] = run; run += v[i]; }
  } else if (bid < 48) {
    const int nt = bid, sl = nt >> 3, f = nt & 7;
    const int kt = t >> 6, lane = t & 63;
    const float* src; int kw, jj;
    if      (sl == 0) { src = w0; kw = 1; jj = 0; }
    else if (sl == 1) { src = w1; kw = 2; jj = 0; }
    else if (sl == 2) { src = w1; kw = 2; jj = 1; }
    else if (sl == 3) { src = w2; kw = 3; jj = 0; }
    else if (sl == 4) { src = w2; kw = 3; jj = 1; }
    else              { src = w2; kw = 3; jj = 2; }
    const int feat  = f * 16 + (lane & 15);
    const int cbase = kt * 32 + ((lane >> 4) << 3);
    __bf16* dst = Wpack + ((((nt * 4 + kt) << 6) + lane) << 3);
#pragma unroll
    for (int j = 0; j < 8; ++j)
      dst[j] = (__bf16)src[(feat * 128 + cbase + j) * kw + jj];
  } else {
    const int idx = (bid - 48) * 256 + t;          // 0..49151
    const int j = idx & 7, lane = (idx >> 3) & 63, rest = idx >> 9;  // 0..95
    const int kt = rest % 12, nt = rest / 12;
    const int o = nt * 16 + (lane & 15);
    const int q = kt * 32 + ((lane >> 4) << 3) + j;
    const float v = lw[o * 384 + q];
    const __bf16 hi = (__bf16)v;
    Lhi[idx] = hi;
    Llo[idx] = (__bf16)(v - (float)hi);
  }
}

// ---------------------------------------------------------------------------
// K2: fused conv + relu + ragged max.  One block per segment.
// Tap shifts done via LDS A-row offsets (rows zero-padded through MT*16+1),
// so each pool accumulates directly — no epilogue shuffles.
// C/D layout (m89-verified): col = lane&15, row = (lane>>4)*4 + reg.
// ---------------------------------------------------------------------------
__global__ __launch_bounds__(256, 4)
void k_conv(const float* __restrict__ x, const int* __restrict__ sizes,
            const int* __restrict__ offsets,
            const float* __restrict__ cb0, const float* __restrict__ cb1,
            const float* __restrict__ cb2,
            const bf16x8* __restrict__ Wpack,
            __bf16* __restrict__ Phi, __bf16* __restrict__ Plo) {
  __shared__ __bf16 xh[66 * 136];   // [row][128 + 8 pad] bf16, 17.9 KB
  const int b = blockIdx.x;
  const int s = sizes[b];
  const long off = offsets[b];
  const int t = threadIdx.x;
  const int MT = (s + 15) >> 4;     // 1..4

  // ---- two-phase staging: 8 predicated float4 loads (all in flight),
  // then convert+store.  Covers rows [0, s). ----
  {
    const int quads = s << 5;       // s*128/4
    float4 v[8];
#pragma unroll
    for (int i = 0; i < 8; ++i) {
      const int qi = t + (i << 8);
      if (qi < quads) {
        const int r = qi >> 5, c = (qi & 31) << 2;
        v[i] = *(const float4*)(x + (off + r) * 128 + c);
      }
    }
#pragma unroll
    for (int i = 0; i < 8; ++i) {
      const int qi = t + (i << 8);
      if (qi < quads) {
        const int r = qi >> 5, c = (qi & 31) << 2;
        bf16x4 h; h[0] = (__bf16)v[i].x; h[1] = (__bf16)v[i].y;
                  h[2] = (__bf16)v[i].z; h[3] = (__bf16)v[i].w;
        *(bf16x4*)&xh[r * 136 + c] = h;
      }
    }
    // zero rows [s, MT*16+2): taps read up to row MT*16+1
    const int zend = MT * 16 + 2;
    const int c = (t & 31) << 2;
    for (int r = s + (t >> 5); r < zend; r += 8)
      *(bf16x4*)&xh[r * 136 + c] =
          bf16x4{(__bf16)0.f, (__bf16)0.f, (__bf16)0.f, (__bf16)0.f};
  }
  __syncthreads();

  const int wid = t >> 6, lane = t & 63;
  const int lo16 = lane & 15, g16 = lane >> 4;

#pragma unroll
  for (int fi = 0; fi < 2; ++fi) {
    const int ft = wid + (fi << 2);
    const int feat = ft * 16 + lo16;

    f32x4 acc[4][3];   // [mtile][pool]
#pragma unroll
    for (int mt = 0; mt < 4; ++mt)
#pragma unroll
      for (int p = 0; p < 3; ++p)
        acc[mt][p] = f32x4{0.f, 0.f, 0.f, 0.f};

#pragma unroll
    for (int kt = 0; kt < 4; ++kt) {
      // slices: 0=w1j0, 1=w2j0, 2=w2j1, 3=w3j0, 4=w3j1, 5=w3j2
      bf16x8 bf[6];
#pragma unroll
      for (int sl = 0; sl < 6; ++sl)
        bf[sl] = Wpack[(((sl * 8 + ft) * 4 + kt) << 6) + lane];
#pragma unroll
      for (int mt = 0; mt < 4; ++mt) {
        if (mt < MT) {   // uniform per block
          const __bf16* ap = &xh[(mt * 16 + lo16) * 136 + kt * 32 + (g16 << 3)];
          const bf16x8 A0 = *(const bf16x8*)ap;
          const bf16x8 A1 = *(const bf16x8*)(ap + 136);
          const bf16x8 A2 = *(const bf16x8*)(ap + 272);
          acc[mt][0] = MFMA16(A0, bf[0], acc[mt][0]);
          acc[mt][1] = MFMA16(A0, bf[1], acc[mt][1]);
          acc[mt][1] = MFMA16(A1, bf[2], acc[mt][1]);
          acc[mt][2] = MFMA16(A0, bf[3], acc[mt][2]);
          acc[mt][2] = MFMA16(A1, bf[4], acc[mt][2]);
          acc[mt][2] = MFMA16(A2, bf[5], acc[mt][2]);
        }
      }
    }

    // ---- epilogue: predicated max over valid rows, butterfly, store ----
    float m1 = -1e30f, m2 = -1e30f, m3 = -1e30f;
#pragma unroll
    for (int mt = 0; mt < 4; ++mt) {
      if (mt >= MT) continue;  // uniform
#pragma unroll
      for (int v = 0; v < 4; ++v) {
        const int lrow = mt * 16 + g16 * 4 + v;
        if (lrow < s)     m1 = fmaxf(m1, acc[mt][0][v]);
        if (lrow < s - 1) m2 = fmaxf(m2, acc[mt][1][v]);
        if (lrow < s - 2) m3 = fmaxf(m3, acc[mt][2][v]);
      }
    }
    m1 = fmaxf(m1, __shfl_xor(m1, 16)); m1 = fmaxf(m1, __shfl_xor(m1, 32));
    m2 = fmaxf(m2, __shfl_xor(m2, 16)); m2 = fmaxf(m2, __shfl_xor(m2, 32));
    m3 = fmaxf(m3, __shfl_xor(m3, 16)); m3 = fmaxf(m3, __shfl_xor(m3, 32));
    if (g16 == 0) {
      // max(relu(h)) == relu(max(Y)+b): bias row-constant, relu monotone
      const float p1 = fmaxf(m1 + cb0[feat], 0.f);
      const float p2 = fmaxf(m2 + cb1[feat], 0.f);
      const float p3 = fmaxf(m3 + cb2[feat], 0.f);
      const __bf16 h1 = (__bf16)p1, h2 = (__bf16)p2, h3 = (__bf16)p3;
      const long row = (long)b * 384;
      Phi[row + feat]       = h1;
      Plo[row + feat]       = (__bf16)(p1 - (float)h1);
      Phi[row + 128 + feat] = h2;
      Plo[row + 128 + feat] = (__bf16)(p2 - (float)h2);
      Phi[row + 256 + feat] = h3;
      Plo[row + 256 + feat] = (__bf16)(p3 - (float)h3);
    }
  }
}

// ---------------------------------------------------------------------------
// K3: out = tanh(P[8192,384] @ lin_w^T + lin_b), split bf16 MFMA (3 products:
// Ph*Wh + Pl*Wh + Ph*Wl -> ~fp32 accuracy).  512 blocks x 16 batch rows.
// ---------------------------------------------------------------------------
__global__ __launch_bounds__(256, 4)
void k_lin(const __bf16* __restrict__ Phi, const __bf16* __restrict__ Plo,
           const bf16x8* __restrict__ Lhi, const bf16x8* __restrict__ Llo,
           const float* __restrict__ lb, float* __restrict__ out) {
  __shared__ __bf16 ph[16 * 392];   // [row][384 + 8 pad]
  __shared__ __bf16 pl[16 * 392];
  const int blk = blockIdx.x, t = threadIdx.x;
  const long rbase = (long)blk * 16;
#pragma unroll
  for (int i = 0; i < 3; ++i) {
    const int ci = t + (i << 8);
    const int r = ci / 48, cc = ci % 48;
    *(int4*)&ph[r * 392 + (cc << 3)] = *(const int4*)&Phi[(rbase + r) * 384 + (cc << 3)];
    *(int4*)&pl[r * 392 + (cc << 3)] = *(const int4*)&Plo[(rbase + r) * 384 + (cc << 3)];
  }
  __syncthreads();
  const int wid = t >> 6, lane = t & 63;
  const int lo16 = lane & 15, g = lane >> 4;
#pragma unroll
  for (int ni = 0; ni < 2; ++ni) {
    const int nt = wid + (ni << 2);
    f32x4 acc = f32x4{0.f, 0.f, 0.f, 0.f};
#pragma unroll
    for (int kt = 0; kt < 12; ++kt) {
      const bf16x8 bh = Lhi[((nt * 12 + kt) << 6) + lane];
      const bf16x8 bl = Llo[((nt * 12 + kt) << 6) + lane];
      const int aoff = lo16 * 392 + kt * 32 + (g << 3);
      const bf16x8 ah = *(const bf16x8*)&ph[aoff];
      const bf16x8 al = *(const bf16x8*)&pl[aoff];
      acc = MFMA16(ah, bh, acc);
      acc = MFMA16(al, bh, acc);
      acc = MFMA16(ah, bl, acc);
    }
    const int o = nt * 16 + lo16;
    const float bias = lb[o];
#pragma unroll
    for (int v = 0; v < 4; ++v) {
      const int r = g * 4 + v;
      const float val = acc[v] + bias;
      out[(rbase + r) * 128 + o] = 1.f - 2.f / (__expf(2.f * val) + 1.f);
    }
  }
}

// ---------------------------------------------------------------------------
extern "C" void kernel_launch(void* const* d_in, const int* in_sizes, int n_in,
                              void* d_out, int out_size, void* d_ws, size_t ws_size,
                              hipStream_t stream) {
  const float* x   = (const float*)d_in[0];
  const int* sizes = (const int*)d_in[1];
  const float* w0  = (const float*)d_in[2];
  const float* cb0 = (const float*)d_in[3];
  const float* w1  = (const float*)d_in[4];
  const float* cb1 = (const float*)d_in[5];
  const float* w2  = (const float*)d_in[6];
  const float* cb2 = (const float*)d_in[7];
  const float* lw  = (const float*)d_in[8];
  const float* lb  = (const float*)d_in[9];

  char* ws = (char*)d_ws;
  size_t o = 0;
  int*    offsets = (int*)ws;                 o += 32768;
  __bf16* Wpack   = (__bf16*)(ws + o);        o += 196608;     // 48*4*64*8*2
  __bf16* Lhi     = (__bf16*)(ws + o);        o += 98304;      // 8*12*64*8*2
  __bf16* Llo     = (__bf16*)(ws + o);        o += 98304;
  __bf16* Phi     = (__bf16*)(ws + o);        o += 8192L * 384 * 2;
  __bf16* Plo     = (__bf16*)(ws + o);        o += 8192L * 384 * 2;

  k_prep<<<241, 256, 0, stream>>>(sizes, offsets, w0, w1, w2, lw, Wpack, Lhi, Llo);
  k_conv<<<8192, 256, 0, stream>>>(x, sizes, offsets, cb0, cb1, cb2,
                                   (const bf16x8*)Wpack, Phi, Plo);
  k_lin<<<512, 256, 0, stream>>>(Phi, Plo, (const bf16x8*)Lhi,
                                 (const bf16x8*)Llo, lb, (float*)d_out);
}